// Round 9
// baseline (242.282 us; speedup 1.0000x reference)
//
#include <hip/hip_runtime.h>
#include <hip/hip_bf16.h>
#include <stdint.h>

#define BB 8
#define SS 4096
#define DD 512
#define HH 8
#define HDIM 64

typedef unsigned short u16;
typedef __attribute__((ext_vector_type(4))) float f32x4;
typedef __attribute__((ext_vector_type(4))) short s16x4;
typedef __attribute__((ext_vector_type(8))) short s16x8;
typedef __attribute__((ext_vector_type(4))) unsigned int u32x4;

__device__ __forceinline__ u16 f2bf(float f) {
  uint32_t x = __builtin_bit_cast(uint32_t, f);
  x += 0x7fffu + ((x >> 16) & 1u);
  return (u16)(x >> 16);
}
__device__ __forceinline__ float bf2f(u16 u) {
  uint32_t x = (uint32_t)u << 16;
  return __builtin_bit_cast(float, x);
}

// async global->LDS, 16B/lane: LDS arg is the WAVE-UNIFORM base; HW adds lane*16.
__device__ __forceinline__ void gld_lds16(const void* g, void* l) {
  __builtin_amdgcn_global_load_lds((const __attribute__((address_space(1))) void*)g,
                                   (__attribute__((address_space(3))) void*)l, 16, 0, 0);
}

// ---------------- f32 -> bf16 bulk conversion (32 B/thread/iter) ----------------
__global__ void cvt_f32_bf16(const float* __restrict__ in, u16* __restrict__ out, int n8) {
  int i = blockIdx.x * blockDim.x + threadIdx.x;
  const int stride = gridDim.x * blockDim.x;
  for (; i < n8; i += stride) {
    const f32x4 a0 = *(const f32x4*)(in + (size_t)i * 8);
    const f32x4 a1 = *(const f32x4*)(in + (size_t)i * 8 + 4);
    s16x8 pk;
#pragma unroll
    for (int j = 0; j < 4; ++j) pk[j] = (short)f2bf(a0[j]);
#pragma unroll
    for (int j = 0; j < 4; ++j) pk[4 + j] = (short)f2bf(a1[j]);
    *(s16x8*)(out + (size_t)i * 8) = pk;
  }
}

// ---------------- weight conversion: 4 x [512*512] f32 -> bf16 ----------------
__global__ void cvt_weights(const float* __restrict__ w0, const float* __restrict__ w1,
                            const float* __restrict__ w2, const float* __restrict__ w3,
                            u16* __restrict__ out) {
  int i = blockIdx.x * blockDim.x + threadIdx.x;
  const int n = DD * DD;
  if (i < n) {
    out[i]         = f2bf(w0[i]);
    out[n + i]     = f2bf(w1[i]);
    out[2 * n + i] = f2bf(w2[i]);
    out[3 * n + i] = f2bf(w3[i]);
  }
}

// ---------------- mask dtype sniff + unpack to canonical u8 ----------------
__global__ void mask_unpack(const void* __restrict__ mraw, uint8_t* __restrict__ mk, int n) {
  __shared__ int bad[3];
  __shared__ int mode;
  const int t = threadIdx.x;
  if (t < 3) bad[t] = 0;
  __syncthreads();
  const uint32_t* w = (const uint32_t*)mraw;
  const uint32_t x = w[t];
  const bool w01 = (x == 0u) || (x == 1u);
  const uint32_t ob = x | (x >> 8) | (x >> 16) | (x >> 24);
  const bool u01 = ((ob & 0xFEu) == 0u);
  if (!w01) atomicAdd(&bad[0], 1);
  if (!u01) atomicAdd(&bad[1], 1);
  __syncthreads();
  if (t == 0) mode = (bad[0] == 0) ? 0 : (bad[1] == 0 ? 1 : 2);
  __syncthreads();
  const int md = mode;
  for (int i = blockIdx.x * 256 + t; i < n; i += gridDim.x * 256) {
    uint8_t v;
    if (md == 0)      v = (uint8_t)(w[i] & 1u);
    else if (md == 1) v = ((const uint8_t*)mraw)[i] ? 1 : 0;
    else              v = (w[i] != 0u) ? 1 : 0;
    mk[i] = v;
  }
}

// ---------------- GEMM: bf16 A, BK=64, DOUBLE-BUFFERED 2-phase pipeline ----------
// C[m][n] = sum_k A[m][k]*Bw[n][k] + bias[n]. A, Bw bf16 [.][K] row-major.
// T3-minimum 2-phase: STAGE(buf^1, t+1) issued BEFORE compute(buf) -> the async
// global_load_lds for tile t+1 are in flight during tile t's MFMA; ONE
// __syncthreads() per tile (its vmcnt(0) drain lands the t+1 stage). LDS layout:
// [row][slot] 128B rows, slot s of row r holds k-granule s^(r&7) (both-sides
// swizzle, measured conflict-free: SQ_LDS_BANK_CONFLICT=0 in R8).
// Grid 1-D: 4 col-siblings of an A row-panel share an XCD (id%8).
template <typename TC>
__global__ __launch_bounds__(256, 2)
void gemm_db(const u16* __restrict__ A, const u16* __restrict__ Bw,
             const float* __restrict__ bias, TC* __restrict__ C,
             int M, int N, int K) {
  __shared__ __align__(16) u16 sA[2][128 * 64];
  __shared__ __align__(16) u16 sB[2][128 * 64];

  const int tid = threadIdx.x;
  const int lane = tid & 63, wv = tid >> 6;
  const int wr = (wv >> 1) * 64, wc = (wv & 1) * 64;
  const int c = lane & 15, g = lane >> 4;
  const int lid = blockIdx.x;
  const int rb = (lid >> 5) * 8 + (lid & 7);
  const int cb = (lid >> 3) & 3;
  const int col0 = cb * 128, row0 = rb * 128;

  // staging: thread covers row (tid>>3)+32i, pre-swizzled k-granule (tid&7)^(row&7)
  const int srB = tid >> 3, cBc = (tid & 7) ^ ((tid >> 3) & 7);
  const u16* a_src = A + (size_t)(row0 + srB) * K + cBc * 8;
  const u16* b_src = Bw + (size_t)(col0 + srB) * K + cBc * 8;

  auto stage = [&](int buf, int ko) {
#pragma unroll
    for (int i = 0; i < 4; ++i)
      gld_lds16(a_src + (size_t)i * 32 * K + ko, (char*)sA[buf] + i * 4096 + wv * 1024);
#pragma unroll
    for (int i = 0; i < 4; ++i)
      gld_lds16(b_src + (size_t)i * 32 * K + ko, (char*)sB[buf] + i * 4096 + wv * 1024);
  };

  f32x4 acc[4][4];
#pragma unroll
  for (int a = 0; a < 4; ++a)
#pragma unroll
    for (int b = 0; b < 4; ++b) acc[a][b] = (f32x4){0.f, 0.f, 0.f, 0.f};

  const int nkt = K / 64;
  stage(0, 0);
  __syncthreads();                       // prologue drain
  int cur = 0;
  for (int kt = 0; kt < nkt; ++kt) {
    if (kt + 1 < nkt) stage(cur ^ 1, (kt + 1) * 64);   // in flight during compute

#pragma unroll
    for (int ks = 0; ks < 2; ++ks) {
      s16x8 af[4], bq[4];
#pragma unroll
      for (int mf = 0; mf < 4; ++mf) {
        const int row = wr + mf * 16 + c;
        af[mf] = *(const s16x8*)&sA[cur][row * 64 + (((ks * 4 + g) ^ (c & 7)) * 8)];
      }
#pragma unroll
      for (int nf = 0; nf < 4; ++nf) {
        const int row = wc + nf * 16 + c;
        bq[nf] = *(const s16x8*)&sB[cur][row * 64 + (((ks * 4 + g) ^ (c & 7)) * 8)];
      }
#pragma unroll
      for (int mf = 0; mf < 4; ++mf)
#pragma unroll
        for (int nf = 0; nf < 4; ++nf)
          acc[mf][nf] = __builtin_amdgcn_mfma_f32_16x16x32_bf16(af[mf], bq[nf], acc[mf][nf], 0, 0, 0);
    }
    __syncthreads();                     // drains vmcnt(0): tile t+1 landed
    cur ^= 1;
  }

  // epilogue: C/D layout col=lane&15, row=4*(lane>>4)+i
#pragma unroll
  for (int nf = 0; nf < 4; ++nf) {
    const int col = col0 + wc + nf * 16 + c;
    const float bv = bias[col];
#pragma unroll
    for (int mf = 0; mf < 4; ++mf) {
#pragma unroll
      for (int i = 0; i < 4; ++i) {
        const int row = row0 + wr + mf * 16 + g * 4 + i;
        const float v = acc[mf][nf][i] + bv;
        if constexpr (sizeof(TC) == 4) C[(size_t)row * N + col] = v;
        else                           C[(size_t)row * N + col] = (TC)f2bf(v);
      }
    }
  }
}

// ---------------- MFMA banded attention v8 (unchanged from R8) ----------------
__device__ __forceinline__ void hilo8(const f32x4& a0, const f32x4& a1, s16x8& h, s16x8& l) {
#pragma unroll
  for (int j = 0; j < 4; ++j) {
    const float f = a0[j];
    const u16 hb = f2bf(f);
    h[j] = (short)hb;
    l[j] = (short)f2bf(f - bf2f(hb));
  }
#pragma unroll
  for (int j = 0; j < 4; ++j) {
    const float f = a1[j];
    const u16 hb = f2bf(f);
    h[4 + j] = (short)hb;
    l[4 + j] = (short)f2bf(f - bf2f(hb));
  }
}

#define ACH 4
#define VSTR 100

__global__ __launch_bounds__(256, 4)
void attn_mfma(const float* __restrict__ Qp, const float* __restrict__ Kp,
               const u16* __restrict__ Vp, const uint8_t* __restrict__ mk,
               u16* __restrict__ O) {
  __shared__ u16 sKh[96 * 72];
  __shared__ u16 sKl[96 * 68];
  __shared__ u16 sVT[64 * VSTR];
  __shared__ u16 sM[96];

  const int bh = blockIdx.x;
  const int b = bh >> 3, h = bh & 7;
  const int base0 = blockIdx.y * (64 * ACH);
  const int tid = threadIdx.x;

  const int wv = tid >> 6, lane = tid & 63;
  const int c = lane & 15, g = lane >> 4;
  const int qloc = wv * 16 + c;
  const int kb = wv * 16;

  const int krow0 = tid >> 3, kj = tid & 7;
  const int kks = kj >> 2, kg2 = kj & 3;
  const int vk0 = tid >> 3, vdg8 = tid & 7;

  f32x4 kA0[3], kA1[3];
  s16x8 vR[3];
  u16 mR = 1;
  f32x4 qn0[2], qn1[2];

  auto issue_loads = [&](int cs) {
#pragma unroll
    for (int it = 0; it < 3; ++it) {
      const int row = krow0 + it * 32;
      const int gr = cs - 16 + row;
      if (gr >= 0 && gr < SS) {
        const float* kp = Kp + ((size_t)(b * SS + gr)) * DD + h * HDIM + kks * 32 + kg2 * 4;
        kA0[it] = *(const f32x4*)kp;
        kA1[it] = *(const f32x4*)(kp + 16);
      } else {
        kA0[it] = (f32x4){0.f, 0.f, 0.f, 0.f};
        kA1[it] = (f32x4){0.f, 0.f, 0.f, 0.f};
      }
    }
#pragma unroll
    for (int it = 0; it < 3; ++it) {
      const int k = vk0 + it * 32;
      const int gr = cs - 16 + k;
      if (gr >= 0 && gr < SS)
        vR[it] = *(const s16x8*)(Vp + ((size_t)(b * SS + gr)) * DD + h * HDIM + vdg8 * 8);
      else
        vR[it] = (s16x8){0, 0, 0, 0, 0, 0, 0, 0};
    }
    if (tid < 96) {
      const int gr = cs - 16 + tid;
      mR = (gr < 0 || gr >= SS || mk[b * SS + gr]) ? 1 : 0;
    }
    const float* qp = Qp + ((size_t)(b * SS + cs + qloc)) * DD + h * HDIM;
#pragma unroll
    for (int ks = 0; ks < 2; ++ks) {
      qn0[ks] = *(const f32x4*)(qp + 32 * ks + 4 * g);
      qn1[ks] = *(const f32x4*)(qp + 32 * ks + 16 + 4 * g);
    }
  };

  auto write_stage = [&]() {
#pragma unroll
    for (int it = 0; it < 3; ++it) {
      const int row = krow0 + it * 32;
      s16x8 hh, ll;
      hilo8(kA0[it], kA1[it], hh, ll);
      *(s16x8*)&sKh[row * 72 + kj * 8] = hh;
      *(s16x4*)&sKl[row * 68 + kj * 8]     = (s16x4){ll[0], ll[1], ll[2], ll[3]};
      *(s16x4*)&sKl[row * 68 + kj * 8 + 4] = (s16x4){ll[4], ll[5], ll[6], ll[7]};
    }
#pragma unroll
    for (int it = 0; it < 3; ++it) {
      const int k = vk0 + it * 32;
#pragma unroll
      for (int i = 0; i < 8; ++i)
        sVT[(vdg8 * 8 + i) * VSTR + k] = (u16)vR[it][i];
    }
    if (tid < 96) sM[tid] = mR;
  };

  issue_loads(base0);
  write_stage();
  __syncthreads();

  for (int t = 0; t < ACH; ++t) {
    const int s0 = base0 + t * 64;
    const int qrow = s0 + qloc;

    s16x8 qh[2], qlo[2];
#pragma unroll
    for (int ks = 0; ks < 2; ++ks) hilo8(qn0[ks], qn1[ks], qh[ks], qlo[ks]);

    if (t + 1 < ACH) issue_loads(base0 + (t + 1) * 64);

    f32x4 st[3];
#pragma unroll
    for (int kt = 0; kt < 3; ++kt) st[kt] = (f32x4){0.f, 0.f, 0.f, 0.f};
    __builtin_amdgcn_s_setprio(1);
#pragma unroll
    for (int kt = 0; kt < 3; ++kt) {
      const int krow = kb + kt * 16 + c;
      const int rb72 = krow * 72;
      const int rb68 = krow * 68;
#pragma unroll
      for (int ks = 0; ks < 2; ++ks) {
        const s16x8 kh = *(const s16x8*)&sKh[rb72 + ks * 32 + g * 8];
        const s16x4 l0 = *(const s16x4*)&sKl[rb68 + ks * 32 + g * 8];
        const s16x4 l1 = *(const s16x4*)&sKl[rb68 + ks * 32 + g * 8 + 4];
        const s16x8 kl = (s16x8){l0[0], l0[1], l0[2], l0[3], l1[0], l1[1], l1[2], l1[3]};
        st[kt] = __builtin_amdgcn_mfma_f32_16x16x32_bf16(kh, qh[ks], st[kt], 0, 0, 0);
        st[kt] = __builtin_amdgcn_mfma_f32_16x16x32_bf16(kh, qlo[ks], st[kt], 0, 0, 0);
        st[kt] = __builtin_amdgcn_mfma_f32_16x16x32_bf16(kl, qh[ks], st[kt], 0, 0, 0);
      }
    }
    __builtin_amdgcn_s_setprio(0);

    float mx = -3.0e9f;
#pragma unroll
    for (int kt = 0; kt < 3; ++kt) {
#pragma unroll
      for (int i = 0; i < 4; ++i) {
        const int delta = kt * 16 + 4 * g + i - 16 - c;
        const int key = kb + kt * 16 + 4 * g + i;
        float v;
        if (delta < -16 || delta > 16) v = -2.0e9f;
        else if (sM[key])              v = -1.0e9f;
        else                           v = st[kt][i];
        st[kt][i] = v;
        mx = fmaxf(mx, v);
      }
    }
    mx = fmaxf(mx, __shfl_xor(mx, 16));
    mx = fmaxf(mx, __shfl_xor(mx, 32));
    float sum = 0.f;
#pragma unroll
    for (int kt = 0; kt < 3; ++kt) {
#pragma unroll
      for (int i = 0; i < 4; ++i) {
        const float e = __expf(st[kt][i] - mx);
        st[kt][i] = e;
        sum += e;
      }
    }
    sum += __shfl_xor(sum, 16);
    sum += __shfl_xor(sum, 32);
    const float inv = 1.f / sum;

    s16x8 ph[2];
#pragma unroll
    for (int i = 0; i < 4; ++i) {
      ph[0][i]     = (short)f2bf(st[0][i]);
      ph[0][4 + i] = (short)f2bf(st[1][i]);
      ph[1][i]     = (short)f2bf(st[2][i]);
      ph[1][4 + i] = 0;
    }

    f32x4 ot[4];
#pragma unroll
    for (int dt = 0; dt < 4; ++dt) ot[dt] = (f32x4){0.f, 0.f, 0.f, 0.f};
    __builtin_amdgcn_s_setprio(1);
#pragma unroll
    for (int dt = 0; dt < 4; ++dt) {
      const int rowb = (dt * 16 + c) * VSTR;
      const s16x4 v0 = *(const s16x4*)&sVT[rowb + kb + 4 * g];
      const s16x4 v1 = *(const s16x4*)&sVT[rowb + kb + 16 + 4 * g];
      const s16x8 vh0 = (s16x8){v0[0], v0[1], v0[2], v0[3], v1[0], v1[1], v1[2], v1[3]};
      ot[dt] = __builtin_amdgcn_mfma_f32_16x16x32_bf16(vh0, ph[0], ot[dt], 0, 0, 0);
      const s16x4 v2 = *(const s16x4*)&sVT[rowb + kb + 32 + 4 * g];
      const s16x8 vh1 = (s16x8){v2[0], v2[1], v2[2], v2[3], 0, 0, 0, 0};
      ot[dt] = __builtin_amdgcn_mfma_f32_16x16x32_bf16(vh1, ph[1], ot[dt], 0, 0, 0);
    }
    __builtin_amdgcn_s_setprio(0);

    u16* op = O + ((size_t)(b * SS + qrow)) * DD + h * HDIM;
#pragma unroll
    for (int dt = 0; dt < 4; ++dt) {
      s16x4 pk;
#pragma unroll
      for (int i = 0; i < 4; ++i) pk[i] = (short)f2bf(ot[dt][i] * inv);
      *(s16x4*)&op[dt * 16 + 4 * g] = pk;
    }

    __syncthreads();
    if (t + 1 < ACH) {
      write_stage();
      __syncthreads();
    }
  }
}

// ---------------- legacy VALU attention (bf16 fallback path only) ----------------
__global__ __launch_bounds__(256)
void attn_win(const u16* __restrict__ Qp, const u16* __restrict__ Kp,
              const u16* __restrict__ Vp, const uint8_t* __restrict__ mk,
              u16* __restrict__ O) {
  constexpr int KR = 96;
  __shared__ float sK[KR][HDIM];
  __shared__ float sV[KR][HDIM];
  __shared__ float sMf[KR];

  const int bh = blockIdx.x;
  const int b = bh >> 3, h = bh & 7;
  const int s0 = blockIdx.y * 64;
  const int tid = threadIdx.x;

  for (int c = tid; c < KR * 16; c += 256) {
    const int row = c >> 4, c4 = c & 15;
    const int gr = s0 - 16 + row;
    float kv[4], vv[4];
    if (gr >= 0 && gr < SS) {
      const size_t base = ((size_t)(b * SS + gr)) * DD + h * HDIM + c4 * 4;
      const s16x4 kk = *(const s16x4*)(Kp + base);
      const s16x4 vx = *(const s16x4*)(Vp + base);
#pragma unroll
      for (int i = 0; i < 4; ++i) { kv[i] = bf2f((u16)kk[i]); vv[i] = bf2f((u16)vx[i]); }
    } else {
#pragma unroll
      for (int i = 0; i < 4; ++i) { kv[i] = 0.f; vv[i] = 0.f; }
    }
#pragma unroll
    for (int i = 0; i < 4; ++i) {
      const int d = c4 * 4 + i;
      const int pd = (d & 15) * 4 + (d >> 4);
      sK[row][pd] = kv[i];
      sV[row][pd] = vv[i];
    }
  }
  for (int r = tid; r < KR; r += 256) {
    const int gr = s0 - 16 + r;
    sMf[r] = (gr < 0 || gr >= SS || mk[b * SS + gr]) ? 1.f : 0.f;
  }
  __syncthreads();

  const int wv = tid >> 6, lane = tid & 63;
  const int g = lane >> 4, d16 = lane & 15;

  for (int rr = 0; rr < 16; rr += 4) {
    const int lr = wv * 16 + rr + g;
    const int srow = s0 + lr;
    const u16* qp = Qp + ((size_t)(b * SS + srow)) * DD + h * HDIM;
    float q0 = bf2f(qp[d16]), q1 = bf2f(qp[d16 + 16]), q2 = bf2f(qp[d16 + 32]), q3 = bf2f(qp[d16 + 48]);
    float sc[33];
#pragma unroll
    for (int o = 0; o < 33; ++o) {
      const f32x4 kk = *(const f32x4*)&sK[lr + o][d16 * 4];
      float p = q0 * kk[0] + q1 * kk[1] + q2 * kk[2] + q3 * kk[3];
      p += __shfl_xor(p, 1);
      p += __shfl_xor(p, 2);
      p += __shfl_xor(p, 4);
      p += __shfl_xor(p, 8);
      sc[o] = (sMf[lr + o] != 0.f) ? -1.0e9f : p;
    }
    float mx = sc[0];
#pragma unroll
    for (int o = 1; o < 33; ++o) mx = fmaxf(mx, sc[o]);
    float sum = 0.f;
#pragma unroll
    for (int o = 0; o < 33; ++o) { const float e = __expf(sc[o] - mx); sc[o] = e; sum += e; }
    const float inv = 1.f / sum;
    f32x4 acc = (f32x4){0.f, 0.f, 0.f, 0.f};
#pragma unroll
    for (int o = 0; o < 33; ++o) {
      const f32x4 vx = *(const f32x4*)&sV[lr + o][d16 * 4];
      acc += (sc[o] * inv) * vx;
    }
    u16* op = O + ((size_t)(b * SS + srow)) * DD + h * HDIM;
    op[d16]      = f2bf(acc[0]);
    op[d16 + 16] = f2bf(acc[1]);
    op[d16 + 32] = f2bf(acc[2]);
    op[d16 + 48] = f2bf(acc[3]);
  }
}

// ---------------- launch ----------------
extern "C" void kernel_launch(void* const* d_in, const int* in_sizes, int n_in,
                              void* d_out, int out_size, void* d_ws, size_t ws_size,
                              hipStream_t stream) {
  const float* query = (const float*)d_in[0];
  const float* key   = (const float*)d_in[1];
  const float* value = (const float*)d_in[2];
  const void*  mraw  = d_in[3];
  const float* Wq = (const float*)d_in[4];
  const float* bq = (const float*)d_in[5];
  const float* Wk = (const float*)d_in[6];
  const float* bk = (const float*)d_in[7];
  const float* Wv = (const float*)d_in[8];
  const float* bv = (const float*)d_in[9];
  const float* Wo = (const float*)d_in[10];
  const float* bo = (const float*)d_in[11];

  const int M = BB * SS, N = DD, K = DD;

  char* ws = (char*)d_ws;
  size_t off = 0;
  auto carve = [&](size_t bytes) -> char* {
    char* p = ws + off;
    off = (off + bytes + 255) & ~(size_t)255;
    return p;
  };
  u16* wAll   = (u16*)carve((size_t)4 * DD * DD * sizeof(u16));
  uint8_t* mk = (uint8_t*)carve((size_t)BB * SS);
  u16* Xb     = (u16*)carve((size_t)M * DD * 2);   // bf16 A staging; aliased as AO later

  const size_t qk_f32 = (size_t)M * DD * 4;
  const size_t v_b16  = (size_t)M * DD * 2;
  const bool f32p = (off + 2 * qk_f32 + v_b16 + 1024) <= ws_size;   // 226 MB total (R4-proven)

  cvt_weights<<<(DD * DD + 255) / 256, 256, 0, stream>>>(Wq, Wk, Wv, Wo, wAll);
  mask_unpack<<<16, 256, 0, stream>>>(mraw, mk, BB * SS);

  const int n8 = M * DD / 8;
  const dim3 gc(2048);
  const dim3 gg((M / 128) * (N / 128));   // 1024, XCD-grouped in-kernel
  const dim3 ga(BB * HH, SS / (64 * ACH));
  u16* AO = Xb;   // Xb dead after V-GEMM; attn writes AO there

  if (f32p) {
    float* Qf = (float*)carve(qk_f32);
    float* Kf = (float*)carve(qk_f32);
    u16*   Vb = (u16*)carve(v_b16);
    cvt_f32_bf16<<<gc, 256, 0, stream>>>(query, Xb, n8);
    gemm_db<float><<<gg, 256, 0, stream>>>(Xb, wAll,               bq, Qf, M, N, K);
    cvt_f32_bf16<<<gc, 256, 0, stream>>>(key, Xb, n8);
    gemm_db<float><<<gg, 256, 0, stream>>>(Xb, wAll + DD * DD,     bk, Kf, M, N, K);
    cvt_f32_bf16<<<gc, 256, 0, stream>>>(value, Xb, n8);
    gemm_db<u16><<<gg, 256, 0, stream>>>(Xb, wAll + 2 * DD * DD, bv, Vb, M, N, K);
    attn_mfma<<<ga, 256, 0, stream>>>(Qf, Kf, Vb, mk, AO);
    gemm_db<float><<<gg, 256, 0, stream>>>(AO, wAll + 3 * DD * DD, bo, (float*)d_out, M, N, K);
  } else {
    const dim3 ga1(BB * HH, SS / 64);
    u16* Qb = (u16*)carve(v_b16);
    u16* Kb = (u16*)carve(v_b16);
    u16* Vb = (u16*)carve(v_b16);
    cvt_f32_bf16<<<gc, 256, 0, stream>>>(query, Xb, n8);
    gemm_db<u16><<<gg, 256, 0, stream>>>(Xb, wAll,               bq, Qb, M, N, K);
    cvt_f32_bf16<<<gc, 256, 0, stream>>>(key, Xb, n8);
    gemm_db<u16><<<gg, 256, 0, stream>>>(Xb, wAll + DD * DD,     bk, Kb, M, N, K);
    cvt_f32_bf16<<<gc, 256, 0, stream>>>(value, Xb, n8);
    gemm_db<u16><<<gg, 256, 0, stream>>>(Xb, wAll + 2 * DD * DD, bv, Vb, M, N, K);
    attn_win<<<ga1, 256, 0, stream>>>(Qb, Kb, Vb, mk, AO);
    gemm_db<float><<<gg, 256, 0, stream>>>(AO, wAll + 3 * DD * DD, bo, (float*)d_out, M, N, K);
  }
}

// Round 10
// 220.799 us; speedup vs baseline: 1.0973x; 1.0973x over previous
//
#include <hip/hip_runtime.h>
#include <hip/hip_bf16.h>
#include <stdint.h>

#define BB 8
#define SS 4096
#define DD 512
#define HH 8
#define HDIM 64

typedef unsigned short u16;
typedef __attribute__((ext_vector_type(4))) float f32x4;
typedef __attribute__((ext_vector_type(4))) short s16x4;
typedef __attribute__((ext_vector_type(8))) short s16x8;
typedef __attribute__((ext_vector_type(4))) unsigned int u32x4;

__device__ __forceinline__ u16 f2bf(float f) {
  uint32_t x = __builtin_bit_cast(uint32_t, f);
  x += 0x7fffu + ((x >> 16) & 1u);
  return (u16)(x >> 16);
}
__device__ __forceinline__ float bf2f(u16 u) {
  uint32_t x = (uint32_t)u << 16;
  return __builtin_bit_cast(float, x);
}
// packed f32x2 -> bf16x2 (RNE): d = {lo:bf16(a), hi:bf16(b)}
__device__ __forceinline__ uint32_t cvtpk(float a, float b) {
  uint32_t d;
  asm("v_cvt_pk_bf16_f32 %0, %1, %2" : "=v"(d) : "v"(a), "v"(b));
  return d;
}

// async global->LDS, 16B/lane: LDS arg is the WAVE-UNIFORM base; HW adds lane*16.
__device__ __forceinline__ void gld_lds16(const void* g, void* l) {
  __builtin_amdgcn_global_load_lds((const __attribute__((address_space(1))) void*)g,
                                   (__attribute__((address_space(3))) void*)l, 16, 0, 0);
}

// 8-byte (4 x u16) LDS load through two 4B-aligned u32 reads (for stride-98 rows).
__device__ __forceinline__ s16x4 ld_u16x4(const u16* p) {
  const uint32_t a = *(const uint32_t*)(p);
  const uint32_t b = *(const uint32_t*)(p + 2);
  s16x4 r;
  r[0] = (short)(a & 0xffff); r[1] = (short)(a >> 16);
  r[2] = (short)(b & 0xffff); r[3] = (short)(b >> 16);
  return r;
}

// ---------------- f32 -> bf16 bulk conversion (fallback path only) ----------------
__global__ void cvt_f32_bf16(const float* __restrict__ in, u16* __restrict__ out, int n8) {
  int i = blockIdx.x * blockDim.x + threadIdx.x;
  const int stride = gridDim.x * blockDim.x;
  for (; i < n8; i += stride) {
    const f32x4 a0 = *(const f32x4*)(in + (size_t)i * 8);
    const f32x4 a1 = *(const f32x4*)(in + (size_t)i * 8 + 4);
    s16x8 pk;
#pragma unroll
    for (int j = 0; j < 4; ++j) pk[j] = (short)f2bf(a0[j]);
#pragma unroll
    for (int j = 0; j < 4; ++j) pk[4 + j] = (short)f2bf(a1[j]);
    *(s16x8*)(out + (size_t)i * 8) = pk;
  }
}

// ---------------- weight conversion: 4 x [512*512] f32 -> bf16 ----------------
__global__ void cvt_weights(const float* __restrict__ w0, const float* __restrict__ w1,
                            const float* __restrict__ w2, const float* __restrict__ w3,
                            u16* __restrict__ out) {
  int i = blockIdx.x * blockDim.x + threadIdx.x;
  const int n = DD * DD;
  if (i < n) {
    out[i]         = f2bf(w0[i]);
    out[n + i]     = f2bf(w1[i]);
    out[2 * n + i] = f2bf(w2[i]);
    out[3 * n + i] = f2bf(w3[i]);
  }
}

// ---------------- mask dtype sniff + unpack to canonical u8 ----------------
__global__ void mask_unpack(const void* __restrict__ mraw, uint8_t* __restrict__ mk, int n) {
  __shared__ int bad[3];
  __shared__ int mode;
  const int t = threadIdx.x;
  if (t < 3) bad[t] = 0;
  __syncthreads();
  const uint32_t* w = (const uint32_t*)mraw;
  const uint32_t x = w[t];
  const bool w01 = (x == 0u) || (x == 1u);
  const uint32_t ob = x | (x >> 8) | (x >> 16) | (x >> 24);
  const bool u01 = ((ob & 0xFEu) == 0u);
  if (!w01) atomicAdd(&bad[0], 1);
  if (!u01) atomicAdd(&bad[1], 1);
  __syncthreads();
  if (t == 0) mode = (bad[0] == 0) ? 0 : (bad[1] == 0 ? 1 : 2);
  __syncthreads();
  const int md = mode;
  for (int i = blockIdx.x * 256 + t; i < n; i += gridDim.x * 256) {
    uint8_t v;
    if (md == 0)      v = (uint8_t)(w[i] & 1u);
    else if (md == 1) v = ((const uint8_t*)mraw)[i] ? 1 : 0;
    else              v = (w[i] != 0u) ? 1 : 0;
    mk[i] = v;
  }
}

// ---------------- GEMM, f32 A fused-convert, double-buffered, 1 barrier/tile ------
// C[m][n] = sum_k A[m][k]*Bw[n][k] + bias[n]. A f32 [M][K]; Bw bf16 [N][K].
// Per tile kt: {issue A f32 reg-loads (t+1), issue B gld_lds (t+1, buf^1)} -> MFMA
// on buf -> cvtpk + swizzled ds_write_b128 of A(t+1) into buf^1 (regs landed during
// compute; buf^1 safe: last read 2 tiles ago) -> ONE __syncthreads (its vmcnt/lgkm
// drain lands B-stage + A-writes). LDS [row][slot], slot s of row r = granule
// s^(r&7) -> 8-lane write/read phases hit 8 distinct slots (R8-measured 0 conflicts).
// Grid 1-D: 4 col-siblings of an A row-panel share an XCD (id%8).
template <typename TC>
__global__ __launch_bounds__(256, 2)
void gemm_f32a(const float* __restrict__ A, const u16* __restrict__ Bw,
               const float* __restrict__ bias, TC* __restrict__ C,
               int M, int N, int K) {
  __shared__ __align__(16) u16 sA[2][128 * 64];
  __shared__ __align__(16) u16 sB[2][128 * 64];

  const int tid = threadIdx.x;
  const int lane = tid & 63, wv = tid >> 6;
  const int wr = (wv >> 1) * 64, wc = (wv & 1) * 64;
  const int c = lane & 15, g = lane >> 4;
  const int lid = blockIdx.x;
  const int rb = (lid >> 5) * 8 + (lid & 7);
  const int cb = (lid >> 3) & 3;
  const int col0 = cb * 128, row0 = rb * 128;

  // B staging (gld_lds, pre-swizzled global granule)
  const int srB = tid >> 3, cBc = (tid & 7) ^ ((tid >> 3) & 7);
  const u16* b_src = Bw + (size_t)(col0 + srB) * K + cBc * 8;
  auto stageB = [&](int buf, int ko) {
#pragma unroll
    for (int i = 0; i < 4; ++i)
      gld_lds16(b_src + (size_t)i * 32 * K + ko, (char*)sB[buf] + i * 4096 + wv * 1024);
  };

  // A f32 reg staging: thread -> granule (tid&7), rows (tid>>3)+{0,32,64,96}
  const int art = tid >> 3, ajt = tid & 7;
  const float* a_src = A + (size_t)(row0 + art) * K + ajt * 8;
  f32x4 aR[4][2];
  auto loadA = [&](int ko) {
#pragma unroll
    for (int i = 0; i < 4; ++i) {
      const float* p = a_src + (size_t)(i * 32) * K + ko;
      aR[i][0] = *(const f32x4*)p;
      aR[i][1] = *(const f32x4*)(p + 4);
    }
  };
  auto writeA = [&](int buf) {
#pragma unroll
    for (int i = 0; i < 4; ++i) {
      const int row = art + i * 32;
      const u32x4 dd = (u32x4){cvtpk(aR[i][0][0], aR[i][0][1]), cvtpk(aR[i][0][2], aR[i][0][3]),
                               cvtpk(aR[i][1][0], aR[i][1][1]), cvtpk(aR[i][1][2], aR[i][1][3])};
      *(s16x8*)&sA[buf][row * 64 + ((ajt ^ (row & 7)) * 8)] = __builtin_bit_cast(s16x8, dd);
    }
  };

  f32x4 acc[4][4];
#pragma unroll
  for (int a = 0; a < 4; ++a)
#pragma unroll
    for (int b = 0; b < 4; ++b) acc[a][b] = (f32x4){0.f, 0.f, 0.f, 0.f};

  const int nkt = K / 64;
  loadA(0);
  stageB(0, 0);
  writeA(0);
  __syncthreads();
  int cur = 0;
  for (int kt = 0; kt < nkt; ++kt) {
    if (kt + 1 < nkt) {
      loadA((kt + 1) * 64);          // f32 A regs for t+1: land during compute
      stageB(cur ^ 1, (kt + 1) * 64);  // B for t+1: in flight during compute
    }

#pragma unroll
    for (int ks = 0; ks < 2; ++ks) {
      s16x8 af[4], bq[4];
#pragma unroll
      for (int mf = 0; mf < 4; ++mf) {
        const int row = wr + mf * 16 + c;
        af[mf] = *(const s16x8*)&sA[cur][row * 64 + (((ks * 4 + g) ^ (c & 7)) * 8)];
      }
#pragma unroll
      for (int nf = 0; nf < 4; ++nf) {
        const int row = wc + nf * 16 + c;
        bq[nf] = *(const s16x8*)&sB[cur][row * 64 + (((ks * 4 + g) ^ (c & 7)) * 8)];
      }
#pragma unroll
      for (int mf = 0; mf < 4; ++mf)
#pragma unroll
        for (int nf = 0; nf < 4; ++nf)
          acc[mf][nf] = __builtin_amdgcn_mfma_f32_16x16x32_bf16(af[mf], bq[nf], acc[mf][nf], 0, 0, 0);
    }
    if (kt + 1 < nkt) writeA(cur ^ 1);   // buf^1 safe: last read 2 tiles ago
    __syncthreads();                     // drains B gld_lds + A ds_writes
    cur ^= 1;
  }

  // epilogue: C/D layout col=lane&15, row=4*(lane>>4)+i
#pragma unroll
  for (int nf = 0; nf < 4; ++nf) {
    const int col = col0 + wc + nf * 16 + c;
    const float bv = bias[col];
#pragma unroll
    for (int mf = 0; mf < 4; ++mf) {
#pragma unroll
      for (int i = 0; i < 4; ++i) {
        const int row = row0 + wr + mf * 16 + g * 4 + i;
        const float v = acc[mf][nf][i] + bv;
        if constexpr (sizeof(TC) == 4) C[(size_t)row * N + col] = v;
        else                           C[(size_t)row * N + col] = (TC)f2bf(v);
      }
    }
  }
}

// ---------------- GEMM: bf16 A, double-buffered (O-projection + fallback) ----------
template <typename TC>
__global__ __launch_bounds__(256, 2)
void gemm_db(const u16* __restrict__ A, const u16* __restrict__ Bw,
             const float* __restrict__ bias, TC* __restrict__ C,
             int M, int N, int K) {
  __shared__ __align__(16) u16 sA[2][128 * 64];
  __shared__ __align__(16) u16 sB[2][128 * 64];

  const int tid = threadIdx.x;
  const int lane = tid & 63, wv = tid >> 6;
  const int wr = (wv >> 1) * 64, wc = (wv & 1) * 64;
  const int c = lane & 15, g = lane >> 4;
  const int lid = blockIdx.x;
  const int rb = (lid >> 5) * 8 + (lid & 7);
  const int cb = (lid >> 3) & 3;
  const int col0 = cb * 128, row0 = rb * 128;

  const int srB = tid >> 3, cBc = (tid & 7) ^ ((tid >> 3) & 7);
  const u16* a_src = A + (size_t)(row0 + srB) * K + cBc * 8;
  const u16* b_src = Bw + (size_t)(col0 + srB) * K + cBc * 8;

  auto stage = [&](int buf, int ko) {
#pragma unroll
    for (int i = 0; i < 4; ++i)
      gld_lds16(a_src + (size_t)i * 32 * K + ko, (char*)sA[buf] + i * 4096 + wv * 1024);
#pragma unroll
    for (int i = 0; i < 4; ++i)
      gld_lds16(b_src + (size_t)i * 32 * K + ko, (char*)sB[buf] + i * 4096 + wv * 1024);
  };

  f32x4 acc[4][4];
#pragma unroll
  for (int a = 0; a < 4; ++a)
#pragma unroll
    for (int b = 0; b < 4; ++b) acc[a][b] = (f32x4){0.f, 0.f, 0.f, 0.f};

  const int nkt = K / 64;
  stage(0, 0);
  __syncthreads();
  int cur = 0;
  for (int kt = 0; kt < nkt; ++kt) {
    if (kt + 1 < nkt) stage(cur ^ 1, (kt + 1) * 64);

#pragma unroll
    for (int ks = 0; ks < 2; ++ks) {
      s16x8 af[4], bq[4];
#pragma unroll
      for (int mf = 0; mf < 4; ++mf) {
        const int row = wr + mf * 16 + c;
        af[mf] = *(const s16x8*)&sA[cur][row * 64 + (((ks * 4 + g) ^ (c & 7)) * 8)];
      }
#pragma unroll
      for (int nf = 0; nf < 4; ++nf) {
        const int row = wc + nf * 16 + c;
        bq[nf] = *(const s16x8*)&sB[cur][row * 64 + (((ks * 4 + g) ^ (c & 7)) * 8)];
      }
#pragma unroll
      for (int mf = 0; mf < 4; ++mf)
#pragma unroll
        for (int nf = 0; nf < 4; ++nf)
          acc[mf][nf] = __builtin_amdgcn_mfma_f32_16x16x32_bf16(af[mf], bq[nf], acc[mf][nf], 0, 0, 0);
    }
    __syncthreads();
    cur ^= 1;
  }

#pragma unroll
  for (int nf = 0; nf < 4; ++nf) {
    const int col = col0 + wc + nf * 16 + c;
    const float bv = bias[col];
#pragma unroll
    for (int mf = 0; mf < 4; ++mf) {
#pragma unroll
      for (int i = 0; i < 4; ++i) {
        const int row = row0 + wr + mf * 16 + g * 4 + i;
        const float v = acc[mf][nf][i] + bv;
        if constexpr (sizeof(TC) == 4) C[(size_t)row * N + col] = v;
        else                           C[(size_t)row * N + col] = (TC)f2bf(v);
      }
    }
  }
}

// ---------------- MFMA banded attention (R8 structure, VSTR=98 conflict fix) -------
__device__ __forceinline__ void hilo8(const f32x4& a0, const f32x4& a1, s16x8& h, s16x8& l) {
#pragma unroll
  for (int j = 0; j < 4; ++j) {
    const float f = a0[j];
    const u16 hb = f2bf(f);
    h[j] = (short)hb;
    l[j] = (short)f2bf(f - bf2f(hb));
  }
#pragma unroll
  for (int j = 0; j < 4; ++j) {
    const float f = a1[j];
    const u16 hb = f2bf(f);
    h[4 + j] = (short)hb;
    l[4 + j] = (short)f2bf(f - bf2f(hb));
  }
}

#define ACH 4
#define VSTR 98   // 8*vdg8 mod 32 -> 4 banks over 8 lanes = 2-way write (free)

__global__ __launch_bounds__(256, 4)
void attn_mfma(const float* __restrict__ Qp, const float* __restrict__ Kp,
               const u16* __restrict__ Vp, const uint8_t* __restrict__ mk,
               u16* __restrict__ O) {
  __shared__ u16 sKh[96 * 72];
  __shared__ u16 sKl[96 * 68];
  __shared__ u16 sVT[64 * VSTR];
  __shared__ u16 sM[96];

  const int bh = blockIdx.x;
  const int b = bh >> 3, h = bh & 7;
  const int base0 = blockIdx.y * (64 * ACH);
  const int tid = threadIdx.x;

  const int wv = tid >> 6, lane = tid & 63;
  const int c = lane & 15, g = lane >> 4;
  const int qloc = wv * 16 + c;
  const int kb = wv * 16;

  const int krow0 = tid >> 3, kj = tid & 7;
  const int kks = kj >> 2, kg2 = kj & 3;
  const int vk0 = tid >> 3, vdg8 = tid & 7;

  f32x4 kA0[3], kA1[3];
  s16x8 vR[3];
  u16 mR = 1;
  f32x4 qn0[2], qn1[2];

  auto issue_loads = [&](int cs) {
#pragma unroll
    for (int it = 0; it < 3; ++it) {
      const int row = krow0 + it * 32;
      const int gr = cs - 16 + row;
      if (gr >= 0 && gr < SS) {
        const float* kp = Kp + ((size_t)(b * SS + gr)) * DD + h * HDIM + kks * 32 + kg2 * 4;
        kA0[it] = *(const f32x4*)kp;
        kA1[it] = *(const f32x4*)(kp + 16);
      } else {
        kA0[it] = (f32x4){0.f, 0.f, 0.f, 0.f};
        kA1[it] = (f32x4){0.f, 0.f, 0.f, 0.f};
      }
    }
#pragma unroll
    for (int it = 0; it < 3; ++it) {
      const int k = vk0 + it * 32;
      const int gr = cs - 16 + k;
      if (gr >= 0 && gr < SS)
        vR[it] = *(const s16x8*)(Vp + ((size_t)(b * SS + gr)) * DD + h * HDIM + vdg8 * 8);
      else
        vR[it] = (s16x8){0, 0, 0, 0, 0, 0, 0, 0};
    }
    if (tid < 96) {
      const int gr = cs - 16 + tid;
      mR = (gr < 0 || gr >= SS || mk[b * SS + gr]) ? 1 : 0;
    }
    const float* qp = Qp + ((size_t)(b * SS + cs + qloc)) * DD + h * HDIM;
#pragma unroll
    for (int ks = 0; ks < 2; ++ks) {
      qn0[ks] = *(const f32x4*)(qp + 32 * ks + 4 * g);
      qn1[ks] = *(const f32x4*)(qp + 32 * ks + 16 + 4 * g);
    }
  };

  auto write_stage = [&]() {
#pragma unroll
    for (int it = 0; it < 3; ++it) {
      const int row = krow0 + it * 32;
      s16x8 hh, ll;
      hilo8(kA0[it], kA1[it], hh, ll);
      *(s16x8*)&sKh[row * 72 + kj * 8] = hh;
      *(s16x4*)&sKl[row * 68 + kj * 8]     = (s16x4){ll[0], ll[1], ll[2], ll[3]};
      *(s16x4*)&sKl[row * 68 + kj * 8 + 4] = (s16x4){ll[4], ll[5], ll[6], ll[7]};
    }
#pragma unroll
    for (int it = 0; it < 3; ++it) {
      const int k = vk0 + it * 32;
#pragma unroll
      for (int i = 0; i < 8; ++i)
        sVT[(vdg8 * 8 + i) * VSTR + k] = (u16)vR[it][i];
    }
    if (tid < 96) sM[tid] = mR;
  };

  issue_loads(base0);
  write_stage();
  __syncthreads();

  for (int t = 0; t < ACH; ++t) {
    const int s0 = base0 + t * 64;
    const int qrow = s0 + qloc;

    s16x8 qh[2], qlo[2];
#pragma unroll
    for (int ks = 0; ks < 2; ++ks) hilo8(qn0[ks], qn1[ks], qh[ks], qlo[ks]);

    if (t + 1 < ACH) issue_loads(base0 + (t + 1) * 64);

    f32x4 st[3];
#pragma unroll
    for (int kt = 0; kt < 3; ++kt) st[kt] = (f32x4){0.f, 0.f, 0.f, 0.f};
    __builtin_amdgcn_s_setprio(1);
#pragma unroll
    for (int kt = 0; kt < 3; ++kt) {
      const int krow = kb + kt * 16 + c;
      const int rb72 = krow * 72;
      const int rb68 = krow * 68;
#pragma unroll
      for (int ks = 0; ks < 2; ++ks) {
        const s16x8 kh = *(const s16x8*)&sKh[rb72 + ks * 32 + g * 8];
        const s16x4 l0 = *(const s16x4*)&sKl[rb68 + ks * 32 + g * 8];
        const s16x4 l1 = *(const s16x4*)&sKl[rb68 + ks * 32 + g * 8 + 4];
        const s16x8 kl = (s16x8){l0[0], l0[1], l0[2], l0[3], l1[0], l1[1], l1[2], l1[3]};
        st[kt] = __builtin_amdgcn_mfma_f32_16x16x32_bf16(kh, qh[ks], st[kt], 0, 0, 0);
        st[kt] = __builtin_amdgcn_mfma_f32_16x16x32_bf16(kh, qlo[ks], st[kt], 0, 0, 0);
        st[kt] = __builtin_amdgcn_mfma_f32_16x16x32_bf16(kl, qh[ks], st[kt], 0, 0, 0);
      }
    }
    __builtin_amdgcn_s_setprio(0);

    float mx = -3.0e9f;
#pragma unroll
    for (int kt = 0; kt < 3; ++kt) {
#pragma unroll
      for (int i = 0; i < 4; ++i) {
        const int delta = kt * 16 + 4 * g + i - 16 - c;
        const int key = kb + kt * 16 + 4 * g + i;
        float v;
        if (delta < -16 || delta > 16) v = -2.0e9f;
        else if (sM[key])              v = -1.0e9f;
        else                           v = st[kt][i];
        st[kt][i] = v;
        mx = fmaxf(mx, v);
      }
    }
    mx = fmaxf(mx, __shfl_xor(mx, 16));
    mx = fmaxf(mx, __shfl_xor(mx, 32));
    float sum = 0.f;
#pragma unroll
    for (int kt = 0; kt < 3; ++kt) {
#pragma unroll
      for (int i = 0; i < 4; ++i) {
        const float e = __expf(st[kt][i] - mx);
        st[kt][i] = e;
        sum += e;
      }
    }
    sum += __shfl_xor(sum, 16);
    sum += __shfl_xor(sum, 32);
    const float inv = 1.f / sum;

    s16x8 ph[2];
#pragma unroll
    for (int i = 0; i < 4; ++i) {
      ph[0][i]     = (short)f2bf(st[0][i]);
      ph[0][4 + i] = (short)f2bf(st[1][i]);
      ph[1][i]     = (short)f2bf(st[2][i]);
      ph[1][4 + i] = 0;
    }

    f32x4 ot[4];
#pragma unroll
    for (int dt = 0; dt < 4; ++dt) ot[dt] = (f32x4){0.f, 0.f, 0.f, 0.f};
    __builtin_amdgcn_s_setprio(1);
#pragma unroll
    for (int dt = 0; dt < 4; ++dt) {
      const int rowb = (dt * 16 + c) * VSTR;
      const s16x4 v0 = ld_u16x4(&sVT[rowb + kb + 4 * g]);
      const s16x4 v1 = ld_u16x4(&sVT[rowb + kb + 16 + 4 * g]);
      const s16x8 vh0 = (s16x8){v0[0], v0[1], v0[2], v0[3], v1[0], v1[1], v1[2], v1[3]};
      ot[dt] = __builtin_amdgcn_mfma_f32_16x16x32_bf16(vh0, ph[0], ot[dt], 0, 0, 0);
      const s16x4 v2 = ld_u16x4(&sVT[rowb + kb + 32 + 4 * g]);
      const s16x8 vh1 = (s16x8){v2[0], v2[1], v2[2], v2[3], 0, 0, 0, 0};
      ot[dt] = __builtin_amdgcn_mfma_f32_16x16x32_bf16(vh1, ph[1], ot[dt], 0, 0, 0);
    }
    __builtin_amdgcn_s_setprio(0);

    u16* op = O + ((size_t)(b * SS + qrow)) * DD + h * HDIM;
#pragma unroll
    for (int dt = 0; dt < 4; ++dt) {
      s16x4 pk;
#pragma unroll
      for (int i = 0; i < 4; ++i) pk[i] = (short)f2bf(ot[dt][i] * inv);
      *(s16x4*)&op[dt * 16 + 4 * g] = pk;
    }

    __syncthreads();
    if (t + 1 < ACH) {
      write_stage();
      __syncthreads();
    }
  }
}

// ---------------- legacy VALU attention (bf16 fallback path only) ----------------
__global__ __launch_bounds__(256)
void attn_win(const u16* __restrict__ Qp, const u16* __restrict__ Kp,
              const u16* __restrict__ Vp, const uint8_t* __restrict__ mk,
              u16* __restrict__ O) {
  constexpr int KR = 96;
  __shared__ float sK[KR][HDIM];
  __shared__ float sV[KR][HDIM];
  __shared__ float sMf[KR];

  const int bh = blockIdx.x;
  const int b = bh >> 3, h = bh & 7;
  const int s0 = blockIdx.y * 64;
  const int tid = threadIdx.x;

  for (int c = tid; c < KR * 16; c += 256) {
    const int row = c >> 4, c4 = c & 15;
    const int gr = s0 - 16 + row;
    float kv[4], vv[4];
    if (gr >= 0 && gr < SS) {
      const size_t base = ((size_t)(b * SS + gr)) * DD + h * HDIM + c4 * 4;
      const s16x4 kk = *(const s16x4*)(Kp + base);
      const s16x4 vx = *(const s16x4*)(Vp + base);
#pragma unroll
      for (int i = 0; i < 4; ++i) { kv[i] = bf2f((u16)kk[i]); vv[i] = bf2f((u16)vx[i]); }
    } else {
#pragma unroll
      for (int i = 0; i < 4; ++i) { kv[i] = 0.f; vv[i] = 0.f; }
    }
#pragma unroll
    for (int i = 0; i < 4; ++i) {
      const int d = c4 * 4 + i;
      const int pd = (d & 15) * 4 + (d >> 4);
      sK[row][pd] = kv[i];
      sV[row][pd] = vv[i];
    }
  }
  for (int r = tid; r < KR; r += 256) {
    const int gr = s0 - 16 + r;
    sMf[r] = (gr < 0 || gr >= SS || mk[b * SS + gr]) ? 1.f : 0.f;
  }
  __syncthreads();

  const int wv = tid >> 6, lane = tid & 63;
  const int g = lane >> 4, d16 = lane & 15;

  for (int rr = 0; rr < 16; rr += 4) {
    const int lr = wv * 16 + rr + g;
    const int srow = s0 + lr;
    const u16* qp = Qp + ((size_t)(b * SS + srow)) * DD + h * HDIM;
    float q0 = bf2f(qp[d16]), q1 = bf2f(qp[d16 + 16]), q2 = bf2f(qp[d16 + 32]), q3 = bf2f(qp[d16 + 48]);
    float sc[33];
#pragma unroll
    for (int o = 0; o < 33; ++o) {
      const f32x4 kk = *(const f32x4*)&sK[lr + o][d16 * 4];
      float p = q0 * kk[0] + q1 * kk[1] + q2 * kk[2] + q3 * kk[3];
      p += __shfl_xor(p, 1);
      p += __shfl_xor(p, 2);
      p += __shfl_xor(p, 4);
      p += __shfl_xor(p, 8);
      sc[o] = (sMf[lr + o] != 0.f) ? -1.0e9f : p;
    }
    float mx = sc[0];
#pragma unroll
    for (int o = 1; o < 33; ++o) mx = fmaxf(mx, sc[o]);
    float sum = 0.f;
#pragma unroll
    for (int o = 0; o < 33; ++o) { const float e = __expf(sc[o] - mx); sc[o] = e; sum += e; }
    const float inv = 1.f / sum;
    f32x4 acc = (f32x4){0.f, 0.f, 0.f, 0.f};
#pragma unroll
    for (int o = 0; o < 33; ++o) {
      const f32x4 vx = *(const f32x4*)&sV[lr + o][d16 * 4];
      acc += (sc[o] * inv) * vx;
    }
    u16* op = O + ((size_t)(b * SS + srow)) * DD + h * HDIM;
    op[d16]      = f2bf(acc[0]);
    op[d16 + 16] = f2bf(acc[1]);
    op[d16 + 32] = f2bf(acc[2]);
    op[d16 + 48] = f2bf(acc[3]);
  }
}

// ---------------- launch ----------------
extern "C" void kernel_launch(void* const* d_in, const int* in_sizes, int n_in,
                              void* d_out, int out_size, void* d_ws, size_t ws_size,
                              hipStream_t stream) {
  const float* query = (const float*)d_in[0];
  const float* key   = (const float*)d_in[1];
  const float* value = (const float*)d_in[2];
  const void*  mraw  = d_in[3];
  const float* Wq = (const float*)d_in[4];
  const float* bq = (const float*)d_in[5];
  const float* Wk = (const float*)d_in[6];
  const float* bk = (const float*)d_in[7];
  const float* Wv = (const float*)d_in[8];
  const float* bv = (const float*)d_in[9];
  const float* Wo = (const float*)d_in[10];
  const float* bo = (const float*)d_in[11];

  const int M = BB * SS, N = DD, K = DD;

  char* ws = (char*)d_ws;
  size_t off = 0;
  auto carve = [&](size_t bytes) -> char* {
    char* p = ws + off;
    off = (off + bytes + 255) & ~(size_t)255;
    return p;
  };
  u16* wAll   = (u16*)carve((size_t)4 * DD * DD * sizeof(u16));
  uint8_t* mk = (uint8_t*)carve((size_t)BB * SS);

  const size_t qk_f32 = (size_t)M * DD * 4;
  const size_t v_b16  = (size_t)M * DD * 2;
  // f32 path footprint: 2*67 + 2*33.5 + 4 MB ~= 205 MB (< R4-proven 226 MB)
  const bool f32p = (off + 2 * qk_f32 + 2 * v_b16 + 1024) <= ws_size;

  cvt_weights<<<(DD * DD + 255) / 256, 256, 0, stream>>>(Wq, Wk, Wv, Wo, wAll);
  mask_unpack<<<16, 256, 0, stream>>>(mraw, mk, BB * SS);

  const dim3 gg((M / 128) * (N / 128));   // 1024, XCD-grouped in-kernel
  const dim3 ga(BB * HH, SS / (64 * ACH));

  if (f32p) {
    float* Qf = (float*)carve(qk_f32);
    float* Kf = (float*)carve(qk_f32);
    u16*   Vb = (u16*)carve(v_b16);
    u16*   AO = (u16*)carve(v_b16);
    gemm_f32a<float><<<gg, 256, 0, stream>>>(query, wAll,               bq, Qf, M, N, K);
    gemm_f32a<float><<<gg, 256, 0, stream>>>(key,   wAll + DD * DD,     bk, Kf, M, N, K);
    gemm_f32a<u16><<<gg, 256, 0, stream>>>(value, wAll + 2 * DD * DD, bv, Vb, M, N, K);
    attn_mfma<<<ga, 256, 0, stream>>>(Qf, Kf, Vb, mk, AO);
    gemm_db<float><<<gg, 256, 0, stream>>>(AO, wAll + 3 * DD * DD, bo, (float*)d_out, M, N, K);
  } else {
    const dim3 ga1(BB * HH, SS / 64);
    const int n8 = M * DD / 8;
    const dim3 gc(2048);
    u16* Xb = (u16*)carve(v_b16);
    u16* Qb = (u16*)carve(v_b16);
    u16* Kb = (u16*)carve(v_b16);
    u16* Vb = (u16*)carve(v_b16);
    u16* AO = Xb;
    cvt_f32_bf16<<<gc, 256, 0, stream>>>(query, Xb, n8);
    gemm_db<u16><<<gg, 256, 0, stream>>>(Xb, wAll,               bq, Qb, M, N, K);
    cvt_f32_bf16<<<gc, 256, 0, stream>>>(key, Xb, n8);
    gemm_db<u16><<<gg, 256, 0, stream>>>(Xb, wAll + DD * DD,     bk, Kb, M, N, K);
    cvt_f32_bf16<<<gc, 256, 0, stream>>>(value, Xb, n8);
    gemm_db<u16><<<gg, 256, 0, stream>>>(Xb, wAll + 2 * DD * DD, bv, Vb, M, N, K);
    attn_win<<<ga1, 256, 0, stream>>>(Qb, Kb, Vb, mk, AO);
    gemm_db<float><<<gg, 256, 0, stream>>>(AO, wAll + 3 * DD * DD, bo, (float*)d_out, M, N, K);
  }
}